// Round 4
// baseline (361.480 us; speedup 1.0000x reference)
//
#include <hip/hip_runtime.h>

// B=8, C=256, H=W=64 -> N=4096, Cq=32. fp32 I/O.
// out = x + attn(x): q=wq x, k=wk x, v=wv x (1x1 conv), softmax over keys (no scale).
//
// v12:
//  - attn: 256-thread blocks (4 waves), 32 q-rows/block, grid 128*ns = 1024
//    -> 4 blocks/CU = 4 independent barrier groups (was 2 lockstepped
//    512-thr blocks). Wave w = key-quarter for QK/softmax, channels
//    64w..64w+63 for PV. Same fixed-MOFF softmax (no max pass), same
//    octet-swizzled P LDS (now 8 KB), setprio around PV.
//  - proj: 64-wide n-tile, ALL 8 k-step x-tiles staged upfront into 64 KB
//    LDS (16 global_load_lds dwordx4 per wave), ONE barrier, then fully
//    unrolled barrier-free K-loop. Kills the 8x serialized HBM-latency
//    drains. Same 3-pass bf16 error-compensated GEMM numerics.
// MFMA 16x16x32_bf16 layouts (HW-verified): A[m=lane&15][k=quad*8+j],
// B[n=lane&15][k=quad*8+j], C/D: col=lane&15, row=quad*4+reg.

#define CH  256
#define DQ  32
#define NSP 4096
#define RWS 320

typedef short short8 __attribute__((ext_vector_type(8)));
typedef float float4v __attribute__((ext_vector_type(4)));

__device__ __forceinline__ unsigned short f2b(float f) {  // RNE f32->bf16
  unsigned int u = __float_as_uint(f);
  unsigned int r = u + 0x7fffu + ((u >> 16) & 1u);
  return (unsigned short)(r >> 16);
}
__device__ __forceinline__ short8 ld8(const unsigned short* p) {
  return *(const short8*)p;
}

// ---------------------------------------------------------------- prep ------
__global__ __launch_bounds__(256) void prep_kernel(
    const float* __restrict__ wq, const float* __restrict__ bq,
    const float* __restrict__ wk, const float* __restrict__ bk,
    const float* __restrict__ wv, const float* __restrict__ bv,
    unsigned short* __restrict__ wh, unsigned short* __restrict__ wl,
    float* __restrict__ ball) {
  int r = blockIdx.x, c = threadIdx.x;
  float v;
  if (r < 32)       v = wq[r * CH + c];
  else if (r < 64)  v = wk[(r - 32) * CH + c];
  else              v = wv[(r - 64) * CH + c];
  unsigned int u = __float_as_uint(v);
  unsigned short hi = (unsigned short)(u >> 16);
  float hf = __uint_as_float(u & 0xffff0000u);
  unsigned short lo = (unsigned short)(__float_as_uint(v - hf) >> 16);
  wh[r * CH + c] = hi;
  wl[r * CH + c] = lo;
  if (c == 0)
    ball[r] = (r < 32) ? bq[r] : (r < 64 ? bk[r - 32] : bv[r - 64]);
}

// ---------------------------------------------------------------- proj ------
// grid (64, 1, ns); block 256 = 4 waves. Block: n-tile 64 x all 320 rows.
// Wave w owns rows 80w..80w+79 (5 r-frags), 4 n-subtiles.
// Staging: all 8 k-step tiles [32c][64n] fp32 -> xs[8][2048] (64 KiB) via
// 16 global_load_lds dwordx4 per wave, then ONE __syncthreads (vmcnt(0)
// drain paced by HBM BW, not 8x serial latency). K-loop: barrier-free,
// fully unrolled: 32 ds_read_b32 (imm offsets, XOR-16 swizzle => 2-way
// banks = free), hi/lo bf16 trunc split in-reg, 10 bf16 B-frag loads
// (whi/wlo, L2-hot), 60 MFMA (3 passes x 5rf x 4ns) per step.
// LDS store mapping: x[c][n] at buf[c*64 + (n ^ 16*((c>>3)&1))]; the XOR is
// wave-uniform per 1KB chunk so the gll source addr pre-swizzles it.
__device__ __forceinline__ void stage_x(const float* xkn, float* buf,
                                        int w, int lane) {
#pragma unroll
  for (int i = 0; i < 2; ++i) {
    const int h  = 2 * w + i;
    const int sw = ((h >> 1) & 1) * 16;
    const int c  = h * 4 + (lane >> 4);
    const int n  = ((lane & 15) * 4) ^ sw;
    const float* gp = xkn + (size_t)c * NSP + n;
    __builtin_amdgcn_global_load_lds(
        (const __attribute__((address_space(1))) unsigned int*)gp,
        (__attribute__((address_space(3))) unsigned int*)(buf + h * 256),
        16, 0, 0);
  }
}

__global__ __launch_bounds__(256, 2) void proj_kernel(
    const float* __restrict__ x,
    const unsigned short* __restrict__ wh, const unsigned short* __restrict__ wl,
    const float* __restrict__ ball,
    unsigned short* __restrict__ qb, unsigned short* __restrict__ kb,
    unsigned short* __restrict__ vb, int b0) {
  __shared__ float xs[8][2048];  // 8 k-steps x [32 c][64 n] fp32 = 64 KiB

  const int bz   = blockIdx.z;
  const int bg   = b0 + bz;
  const int n0   = blockIdx.x * 64;
  const int t    = threadIdx.x;
  const int w    = t >> 6;
  const int lane = t & 63;
  const int col  = lane & 15;
  const int quad = lane >> 4;
  const int r0   = 80 * w;
  const int e    = (quad & 1) * 16;          // read-side XOR (matches c>>3&1)
  const int lbase = quad * 512 + col;        // + (ns*16 ^ e) + j*64

  const float* xb = x + (size_t)bg * CH * NSP;

  // stage ALL x for this block (16 gll dwordx4 per wave, in flight together)
#pragma unroll
  for (int ks = 0; ks < 8; ++ks)
    stage_x(xb + (size_t)(ks * 32) * NSP + n0, xs[ks], w, lane);

  float4v acc[5][4];
#pragma unroll
  for (int rf = 0; rf < 5; ++rf) {
    float bias = ball[r0 + 16 * rf + col];
#pragma unroll
    for (int ns = 0; ns < 4; ++ns)
      acc[rf][ns] = (float4v){bias, bias, bias, bias};
  }

  __syncthreads();  // all 8 tiles resident; only barrier in the kernel

#pragma unroll
  for (int ks = 0; ks < 8; ++ks) {
    const int k0 = ks * 32;

    // B-frags (bf16 weights, hi+lo) for this k-chunk (L2-resident)
    short8 wfh[5], wfl[5];
#pragma unroll
    for (int rf = 0; rf < 5; ++rf) {
      size_t wo = (size_t)(r0 + 16 * rf + col) * CH + k0 + quad * 8;
      wfh[rf] = ld8(wh + wo);
      wfl[rf] = ld8(wl + wo);
    }

    // LDS -> regs, trunc hi/lo split (x = hi + lo, exact to ~2^-16 rel)
    const float* xc = &xs[ks][0];
    short8 ah[4], al[4];
#pragma unroll
    for (int nsb = 0; nsb < 4; ++nsb) {
      const float* xp2 = xc + lbase + ((nsb * 16) ^ e);
#pragma unroll
      for (int j = 0; j < 8; ++j) {
        float v = xp2[j * 64];
        unsigned int u = __float_as_uint(v);
        ah[nsb][j] = (short)(u >> 16);
        float hf = __uint_as_float(u & 0xffff0000u);
        al[nsb][j] = (short)(__float_as_uint(v - hf) >> 16);
      }
    }

    // 3-pass MFMA: hi*whi + lo*whi + hi*wlo
#pragma unroll
    for (int rf = 0; rf < 5; ++rf)
#pragma unroll
      for (int ns = 0; ns < 4; ++ns) {
        acc[rf][ns] = __builtin_amdgcn_mfma_f32_16x16x32_bf16(ah[ns], wfh[rf], acc[rf][ns], 0, 0, 0);
        acc[rf][ns] = __builtin_amdgcn_mfma_f32_16x16x32_bf16(al[ns], wfh[rf], acc[rf][ns], 0, 0, 0);
        acc[rf][ns] = __builtin_amdgcn_mfma_f32_16x16x32_bf16(ah[ns], wfl[rf], acc[rf][ns], 0, 0, 0);
      }
  }

  // epilogue: D col=lane&15 -> output row r; D row=quad*4+reg -> spatial n
#pragma unroll
  for (int rf = 0; rf < 5; ++rf) {
    const int rr = r0 + 16 * rf + col;
    const int rb = r0 + 16 * rf;  // wave-uniform category (boundaries are x16)
#pragma unroll
    for (int ns = 0; ns < 4; ++ns) {
      const int nb = n0 + ns * 16 + quad * 4;
      if (rb < 32) {
#pragma unroll
        for (int reg = 0; reg < 4; ++reg)
          qb[((size_t)bz * NSP + nb + reg) * DQ + rr] = f2b(acc[rf][ns][reg]);
      } else if (rb < 64) {
#pragma unroll
        for (int reg = 0; reg < 4; ++reg)
          kb[((size_t)bz * NSP + nb + reg) * DQ + (rr - 32)] = f2b(acc[rf][ns][reg]);
      } else {
        ushort4 o = {f2b(acc[rf][ns][0]), f2b(acc[rf][ns][1]),
                     f2b(acc[rf][ns][2]), f2b(acc[rf][ns][3])};
        *(ushort4*)&vb[((size_t)bz * CH + (rr - 64)) * NSP + nb] = o;
      }
    }
  }
}

// ---------------------------------------------------------------- attn ------
// grid (128*ns) of 256 threads (4 waves). bl = blockIdx%ns (XCD-pins batch);
// i0 = (blockIdx/ns)*32. Wave w: keys 16w..16w+15 of each 64-key chunk for
// QK/softmax; channels 64w..64w+63 for PV. Fixed softmax shift MOFF (no max
// pass). Per 64-key chunk: QK (2 MFMA) -> p=exp2(s*LOG2E-MOFF), lp+=p,
// P bf16 -> swizzled LDS dbuf -> ONE barrier -> 4 pf ds_reads + 16 PV MFMAs
// (setprio 1). P layout: idx(cp,row,k) = cp*2048 + row*64 +
// ((k>>3) ^ (row&7))*8 + (k&7); rows 0..31.
__global__ __launch_bounds__(256, 4) void attn_kernel(
    const float* __restrict__ x,
    const unsigned short* __restrict__ qb, const unsigned short* __restrict__ kb,
    const unsigned short* __restrict__ vb,
    float* __restrict__ out, int b0, int ns) {
  __shared__ unsigned short ps[2 * 32 * 64];  // P bf16 dbuf, swizzled, 8 KiB
  __shared__ float buf[4][32];                // per-kq l partials
  __shared__ float lf[32];                    // 1/l per row

  const int bl   = blockIdx.x % ns;
  const int bg   = b0 + bl;
  const int i0   = (blockIdx.x / ns) * 32;
  const int t    = threadIdx.x;
  const int w    = t >> 6;       // key-quarter for QK; channel quarter for PV
  const int lane = t & 63;
  const int col  = lane & 15;
  const int quad = lane >> 4;
  const float LOG2E = 1.4426950408889634f;
  const float MOFF  = 57.70780163555852f;  // 40 * log2(e); softmax shift

  const unsigned short* qbb = qb + (size_t)bl * NSP * DQ;
  const unsigned short* kbb = kb + (size_t)bl * NSP * DQ;
  const unsigned short* vbb = vb + (size_t)bl * CH * NSP;

  short8 qf[2];
#pragma unroll
  for (int rgp = 0; rgp < 2; ++rgp)
    qf[rgp] = ld8(qbb + (size_t)(i0 + 16 * rgp + col) * DQ + quad * 8);
  const float4v z4 = (float4v){0.f, 0.f, 0.f, 0.f};

  // write-side swizzle constants: row&7 = 4*(quad&1)+reg (p1: +16 rows, same)
  const int kb8 = 2 * w + (col >> 3);    // k-octet
  const int ci  = col & 7;               // in-octet
  const int q4  = 4 * (quad & 1);
  // read-side: o' = quad ^ (col&7), rg-invariant; pf1 flips bit2 (ob^4)
  const int ob  = quad ^ ci;

  // ---------------- single pass: P + PV, deferred l ----------------
  float4v acc[2][4];  // [row-group 16][channel-tile]
#pragma unroll
  for (int rg = 0; rg < 2; ++rg)
#pragma unroll
    for (int ct = 0; ct < 4; ++ct) acc[rg][ct] = z4;
  float lp[2][4];
#pragma unroll
  for (int rgp = 0; rgp < 2; ++rgp)
#pragma unroll
    for (int reg = 0; reg < 4; ++reg) lp[rgp][reg] = 0.0f;

  short8 kf = ld8(kbb + (size_t)(16 * w + col) * DQ + quad * 8);
  for (int j0 = 0; j0 < NSP; j0 += 64) {
    const int cp = (j0 >> 6) & 1;
    // V fragments for this chunk (consumed after the barrier)
    short8 vf[4][2];
#pragma unroll
    for (int ct = 0; ct < 4; ++ct)
#pragma unroll
      for (int h = 0; h < 2; ++h)
        vf[ct][h] = ld8(vbb + (size_t)(64 * w + 16 * ct + col) * NSP
                        + j0 + 32 * h + quad * 8);
    float4v c0 = __builtin_amdgcn_mfma_f32_16x16x32_bf16(qf[0], kf, z4, 0, 0, 0);
    float4v c1 = __builtin_amdgcn_mfma_f32_16x16x32_bf16(qf[1], kf, z4, 0, 0, 0);
    int jn = (j0 + 64 < NSP) ? j0 + 64 : 0;
    short8 kfn = ld8(kbb + (size_t)(jn + 16 * w + col) * DQ + quad * 8);
    unsigned short* pw = &ps[cp * 2048 + (quad * 4) * 64 + ci];
#pragma unroll
    for (int reg = 0; reg < 4; ++reg) {
      float p0 = __builtin_amdgcn_exp2f(fmaf(c0[reg], LOG2E, -MOFF));
      float p1 = __builtin_amdgcn_exp2f(fmaf(c1[reg], LOG2E, -MOFF));
      lp[0][reg] += p0;
      lp[1][reg] += p1;
      const int so = reg * 64 + (kb8 ^ (q4 + reg)) * 8;
      pw[so]        = f2b(p0);
      pw[so + 1024] = f2b(p1);   // row+16: (row&7) unchanged -> same octet swz
    }
    __syncthreads();   // P(cp) visible; ps-cp readers from 2 chunks ago done

    const short8* pb0 = (const short8*)&ps[cp * 2048 + col * 64 + ob * 8];
    const short8* pb1 = (const short8*)&ps[cp * 2048 + col * 64 + (ob ^ 4) * 8];
    __builtin_amdgcn_s_setprio(1);
#pragma unroll
    for (int rg = 0; rg < 2; ++rg) {
      short8 pf0 = pb0[rg * 128];   // +16 rows per rg (2048 B)
      short8 pf1 = pb1[rg * 128];
#pragma unroll
      for (int ct = 0; ct < 4; ++ct) {
        acc[rg][ct] = __builtin_amdgcn_mfma_f32_16x16x32_bf16(pf0, vf[ct][0], acc[rg][ct], 0, 0, 0);
        acc[rg][ct] = __builtin_amdgcn_mfma_f32_16x16x32_bf16(pf1, vf[ct][1], acc[rg][ct], 0, 0, 0);
      }
    }
    __builtin_amdgcn_s_setprio(0);
    kf = kfn;
  }

  // ---------------- l reduction ----------------
#pragma unroll
  for (int rgp = 0; rgp < 2; ++rgp)
#pragma unroll
    for (int reg = 0; reg < 4; ++reg) {
#pragma unroll
      for (int mask = 1; mask <= 8; mask <<= 1)
        lp[rgp][reg] += __shfl_xor(lp[rgp][reg], mask);
    }
  if (col == 0) {
#pragma unroll
    for (int rgp = 0; rgp < 2; ++rgp)
#pragma unroll
      for (int reg = 0; reg < 4; ++reg)
        buf[w][16 * rgp + quad * 4 + reg] = lp[rgp][reg];
  }
  __syncthreads();
  if (w == 0 && col == 0) {
#pragma unroll
    for (int rgp = 0; rgp < 2; ++rgp)
#pragma unroll
      for (int reg = 0; reg < 4; ++reg) {
        int row = 16 * rgp + quad * 4 + reg;
        lf[row] = 1.0f / (buf[0][row] + buf[1][row] + buf[2][row] + buf[3][row]);
      }
  }
  __syncthreads();

  // ---------------- epilogue: normalize + residual + store ----------------
#pragma unroll
  for (int rg = 0; rg < 2; ++rg) {
    float linv[4];
#pragma unroll
    for (int reg = 0; reg < 4; ++reg)
      linv[reg] = lf[16 * rg + quad * 4 + reg];
#pragma unroll
    for (int ct = 0; ct < 4; ++ct) {
      int c  = 64 * w + 16 * ct + col;
      int ib = i0 + 16 * rg + quad * 4;
      size_t idx = ((size_t)bg * CH + c) * NSP + ib;
      float4 xr = *(const float4*)&x[idx];
      float4 o;
      o.x = acc[rg][ct][0] * linv[0] + xr.x;
      o.y = acc[rg][ct][1] * linv[1] + xr.y;
      o.z = acc[rg][ct][2] * linv[2] + xr.z;
      o.w = acc[rg][ct][3] * linv[3] + xr.w;
      *(float4*)&out[idx] = o;
    }
  }
}

// ---------------------------------------------------------------- launch ----
extern "C" void kernel_launch(void* const* d_in, const int* in_sizes, int n_in,
                              void* d_out, int out_size, void* d_ws, size_t ws_size,
                              hipStream_t stream) {
  (void)in_sizes; (void)n_in; (void)out_size;
  const float* x  = (const float*)d_in[0];
  const float* wq = (const float*)d_in[1];
  const float* bq = (const float*)d_in[2];
  const float* wk = (const float*)d_in[3];
  const float* bk = (const float*)d_in[4];
  const float* wv = (const float*)d_in[5];
  const float* bv = (const float*)d_in[6];
  float* out = (float*)d_out;

  const size_t WALL_B = (size_t)RWS * CH * sizeof(float) + 4096;  // wh+wl+ball
  const size_t QB_B = (size_t)NSP * DQ * sizeof(unsigned short);  // 256 KiB
  const size_t VB_B = (size_t)CH * NSP * sizeof(unsigned short);  //   2 MiB
  const size_t PER_B = 2 * QB_B + VB_B;                           // 2.5 MiB/batch

  int ns = 8;
  while (ns > 1 && WALL_B + (size_t)ns * PER_B > ws_size) ns >>= 1;

  char* ws = (char*)d_ws;
  unsigned short* wh = (unsigned short*)ws;
  unsigned short* wl = wh + (size_t)RWS * CH;
  float* ball = (float*)(ws + (size_t)RWS * CH * 2 * sizeof(unsigned short));
  char* qkv = ws + WALL_B;
  unsigned short* qb = (unsigned short*)qkv;
  unsigned short* kb = (unsigned short*)(qkv + (size_t)ns * QB_B);
  unsigned short* vb = (unsigned short*)(qkv + (size_t)ns * 2 * QB_B);

  prep_kernel<<<dim3(RWS), dim3(256), 0, stream>>>(wq, bq, wk, bk, wv, bv, wh, wl, ball);
  for (int b0 = 0; b0 < 8; b0 += ns) {
    proj_kernel<<<dim3(64, 1, ns), dim3(256), 0, stream>>>(
        x, wh, wl, ball, qb, kb, vb, b0);
    attn_kernel<<<dim3(128 * ns), dim3(256), 0, stream>>>(
        x, qb, kb, vb, out, b0, ns);
  }
}

// Round 5
// 258.130 us; speedup vs baseline: 1.4004x; 1.4004x over previous
//
#include <hip/hip_runtime.h>

// B=8, C=256, H=W=64 -> N=4096, Cq=32. fp32 I/O.
// out = x + attn(x): q=wq x, k=wk x, v=wv x (1x1 conv), softmax over keys (no scale).
//
// v13:
//  - attn: back to v11 shape (512 thr, 8 waves, 64 rows/block, wave = rh x kq)
//    but 128-key chunks: one barrier per 128 keys, 8 V-ld8 + 2 K-ld8 issued
//    up front per iteration. P LDS = [2][64][128] bf16 (32 KB) with the same
//    octet XOR swizzle (phys k-octet = s*8 + (octL ^ (row&7))). Fixed-MOFF
//    softmax (no max pass), setprio around PV.
//  - proj: v12 body (all-upfront x staging, one barrier, unrolled K-loop);
//    q/k epilogue scatter replaced by LDS transpose (reuses xs) + coalesced
//    ushort4 stores (wave 0 only; v path already coalesced).
// MFMA 16x16x32_bf16 layouts (HW-verified): A[m=lane&15][k=quad*8+j],
// B[n=lane&15][k=quad*8+j], C/D: col=lane&15, row=quad*4+reg.

#define CH  256
#define DQ  32
#define NSP 4096
#define RWS 320

typedef short short8 __attribute__((ext_vector_type(8)));
typedef float float4v __attribute__((ext_vector_type(4)));

__device__ __forceinline__ unsigned short f2b(float f) {  // RNE f32->bf16
  unsigned int u = __float_as_uint(f);
  unsigned int r = u + 0x7fffu + ((u >> 16) & 1u);
  return (unsigned short)(r >> 16);
}
__device__ __forceinline__ short8 ld8(const unsigned short* p) {
  return *(const short8*)p;
}

// ---------------------------------------------------------------- prep ------
__global__ __launch_bounds__(256) void prep_kernel(
    const float* __restrict__ wq, const float* __restrict__ bq,
    const float* __restrict__ wk, const float* __restrict__ bk,
    const float* __restrict__ wv, const float* __restrict__ bv,
    unsigned short* __restrict__ wh, unsigned short* __restrict__ wl,
    float* __restrict__ ball) {
  int r = blockIdx.x, c = threadIdx.x;
  float v;
  if (r < 32)       v = wq[r * CH + c];
  else if (r < 64)  v = wk[(r - 32) * CH + c];
  else              v = wv[(r - 64) * CH + c];
  unsigned int u = __float_as_uint(v);
  unsigned short hi = (unsigned short)(u >> 16);
  float hf = __uint_as_float(u & 0xffff0000u);
  unsigned short lo = (unsigned short)(__float_as_uint(v - hf) >> 16);
  wh[r * CH + c] = hi;
  wl[r * CH + c] = lo;
  if (c == 0)
    ball[r] = (r < 32) ? bq[r] : (r < 64 ? bk[r - 32] : bv[r - 64]);
}

// ---------------------------------------------------------------- proj ------
// grid (64, 1, ns); block 256 = 4 waves. Block: n-tile 64 x all 320 rows.
// Wave w owns rows 80w..80w+79 (5 r-frags), 4 n-subtiles.
// All 8 k-step x-tiles staged upfront into 64 KiB LDS (16 gll dwordx4 per
// wave), ONE barrier, then fully unrolled barrier-free K-loop.
// Epilogue: v rows -> direct ushort4 stores (coalesced). q/k rows (all in
// wave 0) -> LDS transpose [n][r] (reusing xs, pad 68) -> ushort4 stores
// fully coalesced along dq.
__device__ __forceinline__ void stage_x(const float* xkn, float* buf,
                                        int w, int lane) {
#pragma unroll
  for (int i = 0; i < 2; ++i) {
    const int h  = 2 * w + i;
    const int sw = ((h >> 1) & 1) * 16;
    const int c  = h * 4 + (lane >> 4);
    const int n  = ((lane & 15) * 4) ^ sw;
    const float* gp = xkn + (size_t)c * NSP + n;
    __builtin_amdgcn_global_load_lds(
        (const __attribute__((address_space(1))) unsigned int*)gp,
        (__attribute__((address_space(3))) unsigned int*)(buf + h * 256),
        16, 0, 0);
  }
}

__global__ __launch_bounds__(256, 2) void proj_kernel(
    const float* __restrict__ x,
    const unsigned short* __restrict__ wh, const unsigned short* __restrict__ wl,
    const float* __restrict__ ball,
    unsigned short* __restrict__ qb, unsigned short* __restrict__ kb,
    unsigned short* __restrict__ vb, int b0) {
  __shared__ float xs[8][2048];  // 8 k-steps x [32 c][64 n] fp32 = 64 KiB

  const int bz   = blockIdx.z;
  const int bg   = b0 + bz;
  const int n0   = blockIdx.x * 64;
  const int t    = threadIdx.x;
  const int w    = t >> 6;
  const int lane = t & 63;
  const int col  = lane & 15;
  const int quad = lane >> 4;
  const int r0   = 80 * w;
  const int e    = (quad & 1) * 16;          // read-side XOR (matches c>>3&1)
  const int lbase = quad * 512 + col;        // + (ns*16 ^ e) + j*64

  const float* xb = x + (size_t)bg * CH * NSP;

  // stage ALL x for this block (16 gll dwordx4 per wave, in flight together)
#pragma unroll
  for (int ks = 0; ks < 8; ++ks)
    stage_x(xb + (size_t)(ks * 32) * NSP + n0, xs[ks], w, lane);

  float4v acc[5][4];
#pragma unroll
  for (int rf = 0; rf < 5; ++rf) {
    float bias = ball[r0 + 16 * rf + col];
#pragma unroll
    for (int ns = 0; ns < 4; ++ns)
      acc[rf][ns] = (float4v){bias, bias, bias, bias};
  }

  __syncthreads();  // all 8 tiles resident

#pragma unroll
  for (int ks = 0; ks < 8; ++ks) {
    const int k0 = ks * 32;

    // B-frags (bf16 weights, hi+lo) for this k-chunk (L2-resident)
    short8 wfh[5], wfl[5];
#pragma unroll
    for (int rf = 0; rf < 5; ++rf) {
      size_t wo = (size_t)(r0 + 16 * rf + col) * CH + k0 + quad * 8;
      wfh[rf] = ld8(wh + wo);
      wfl[rf] = ld8(wl + wo);
    }

    // LDS -> regs, trunc hi/lo split (x = hi + lo, exact to ~2^-16 rel)
    const float* xc = &xs[ks][0];
    short8 ah[4], al[4];
#pragma unroll
    for (int nsb = 0; nsb < 4; ++nsb) {
      const float* xp2 = xc + lbase + ((nsb * 16) ^ e);
#pragma unroll
      for (int j = 0; j < 8; ++j) {
        float v = xp2[j * 64];
        unsigned int u = __float_as_uint(v);
        ah[nsb][j] = (short)(u >> 16);
        float hf = __uint_as_float(u & 0xffff0000u);
        al[nsb][j] = (short)(__float_as_uint(v - hf) >> 16);
      }
    }

    // 3-pass MFMA: hi*whi + lo*whi + hi*wlo
#pragma unroll
    for (int rf = 0; rf < 5; ++rf)
#pragma unroll
      for (int ns = 0; ns < 4; ++ns) {
        acc[rf][ns] = __builtin_amdgcn_mfma_f32_16x16x32_bf16(ah[ns], wfh[rf], acc[rf][ns], 0, 0, 0);
        acc[rf][ns] = __builtin_amdgcn_mfma_f32_16x16x32_bf16(al[ns], wfh[rf], acc[rf][ns], 0, 0, 0);
        acc[rf][ns] = __builtin_amdgcn_mfma_f32_16x16x32_bf16(ah[ns], wfl[rf], acc[rf][ns], 0, 0, 0);
      }
  }

  __syncthreads();  // xs reads done by ALL waves; safe to reuse as qt

  // ---- v rows: direct coalesced stores (waves 0..3 own rows >=64) ----
#pragma unroll
  for (int rf = 0; rf < 5; ++rf) {
    const int rr = r0 + 16 * rf + col;
    const int rb = r0 + 16 * rf;  // wave-uniform category (boundaries x16)
    if (rb >= 64) {
#pragma unroll
      for (int ns = 0; ns < 4; ++ns) {
        const int nb = n0 + ns * 16 + quad * 4;
        ushort4 o = {f2b(acc[rf][ns][0]), f2b(acc[rf][ns][1]),
                     f2b(acc[rf][ns][2]), f2b(acc[rf][ns][3])};
        *(ushort4*)&vb[((size_t)bz * CH + (rr - 64)) * NSP + nb] = o;
      }
    }
  }

  // ---- q/k rows: wave 0 only (rows 0..63 all live in wave 0) ----
  if (w == 0) {
    unsigned short* qt = (unsigned short*)&xs[0][0];  // [64 n][68 r] u16
#pragma unroll
    for (int rf = 0; rf < 4; ++rf) {
      const int rr = 16 * rf + col;  // 0..63: q 0..31, k 32..63
#pragma unroll
      for (int ns = 0; ns < 4; ++ns) {
#pragma unroll
        for (int reg = 0; reg < 4; ++reg)
          qt[(16 * ns + quad * 4 + reg) * 68 + rr] = f2b(acc[rf][ns][reg]);
      }
    }
    // same-wave ds write->read; compiler inserts lgkmcnt
    const int nl = lane >> 3;           // 0..7
    const int c4 = (lane & 7) * 4;      // 0..28
#pragma unroll
    for (int it = 0; it < 8; ++it) {
      const int n = 8 * it + nl;
      ushort4 vq = *(const ushort4*)&qt[n * 68 + c4];
      ushort4 vk = *(const ushort4*)&qt[n * 68 + 32 + c4];
      *(ushort4*)&qb[((size_t)bz * NSP + n0 + n) * DQ + c4] = vq;
      *(ushort4*)&kb[((size_t)bz * NSP + n0 + n) * DQ + c4] = vk;
    }
  }
}

// ---------------------------------------------------------------- attn ------
// grid (64*ns) of 512 threads (8 waves). bl = blockIdx%ns (XCD-pins batch);
// i0 = (blockIdx/ns)*64. Wave w: rh=w>>2 (rows 32rh..+32), kq=w&3 (keys
// 16kq..+16 of each 64-key sub-chunk) for QK/softmax; channels 32w..+32 for
// PV. Fixed softmax shift MOFF (no max pass). Per 128-key chunk: 8 V-ld8 +
// QK (4 MFMA, K prefetched) -> p=exp2(s*LOG2E-MOFF), lp+=p, P bf16 ->
// swizzled LDS dbuf -> ONE barrier -> 16 pf ds_reads + 32 PV MFMAs
// (setprio 1). P layout (shorts): idx(cp,row,k) = cp*8192 + row*128 +
// s*64 + ((octL ^ (row&7))*8) + (k&7), octL = (k&63)>>3, s = k>>6.
__global__ __launch_bounds__(512, 4) void attn_kernel(
    const float* __restrict__ x,
    const unsigned short* __restrict__ qb, const unsigned short* __restrict__ kb,
    const unsigned short* __restrict__ vb,
    float* __restrict__ out, int b0, int ns) {
  __shared__ unsigned short ps[2 * 64 * 128];  // P bf16 dbuf, swizzled, 32 KiB
  __shared__ float buf[4][64];                 // per-kq l partials
  __shared__ float lf[64];                     // 1/l per row

  const int bl   = blockIdx.x % ns;
  const int bg   = b0 + bl;
  const int i0   = (blockIdx.x / ns) * 64;
  const int t    = threadIdx.x;
  const int w    = t >> 6;
  const int rh   = w >> 2;
  const int kq   = w & 3;
  const int lane = t & 63;
  const int col  = lane & 15;
  const int quad = lane >> 4;
  const float LOG2E = 1.4426950408889634f;
  const float MOFF  = 57.70780163555852f;  // 40 * log2(e); softmax shift

  const unsigned short* qbb = qb + (size_t)bl * NSP * DQ;
  const unsigned short* kbb = kb + (size_t)bl * NSP * DQ;
  const unsigned short* vbb = vb + (size_t)bl * CH * NSP;

  short8 qf[2];
#pragma unroll
  for (int rgp = 0; rgp < 2; ++rgp)
    qf[rgp] = ld8(qbb + (size_t)(i0 + 32 * rh + 16 * rgp + col) * DQ + quad * 8);
  const float4v z4 = (float4v){0.f, 0.f, 0.f, 0.f};

  // write-side swizzle constants: row&7 = 4*(quad&1)+reg (p1: +16 rows, same)
  const int kb8 = 2 * kq + (col >> 3);   // local k-octet (0..7)
  const int ci  = col & 7;               // in-octet
  const int q4  = 4 * (quad & 1);
  // read-side: oct' low3 = quad ^ (col&7), rg-invariant; k-half flips bit2
  const int ob  = quad ^ ci;

  float4v acc[4][2];  // [row-group 16][channel-tile]
#pragma unroll
  for (int rg = 0; rg < 4; ++rg)
#pragma unroll
    for (int ct = 0; ct < 2; ++ct) acc[rg][ct] = z4;
  float lp[2][4];
#pragma unroll
  for (int rgp = 0; rgp < 2; ++rgp)
#pragma unroll
    for (int reg = 0; reg < 4; ++reg) lp[rgp][reg] = 0.0f;

  short8 kf[2];
#pragma unroll
  for (int s = 0; s < 2; ++s)
    kf[s] = ld8(kbb + (size_t)(64 * s + 16 * kq + col) * DQ + quad * 8);

  for (int j0 = 0; j0 < NSP; j0 += 128) {
    const int cp = (j0 >> 7) & 1;
    // V fragments for both sub-chunks (consumed after the barrier)
    short8 vf[2][2][2];
#pragma unroll
    for (int s = 0; s < 2; ++s)
#pragma unroll
      for (int ct = 0; ct < 2; ++ct)
#pragma unroll
        for (int h = 0; h < 2; ++h)
          vf[s][ct][h] = ld8(vbb + (size_t)(32 * w + 16 * ct + col) * NSP
                             + j0 + 64 * s + 32 * h + quad * 8);
    // QK for both sub-chunks
    float4v c_[2][2];
#pragma unroll
    for (int s = 0; s < 2; ++s) {
      c_[s][0] = __builtin_amdgcn_mfma_f32_16x16x32_bf16(qf[0], kf[s], z4, 0, 0, 0);
      c_[s][1] = __builtin_amdgcn_mfma_f32_16x16x32_bf16(qf[1], kf[s], z4, 0, 0, 0);
    }
    // prefetch K for next chunk
    const int jn = (j0 + 128 < NSP) ? j0 + 128 : 0;
#pragma unroll
    for (int s = 0; s < 2; ++s)
      kf[s] = ld8(kbb + (size_t)(jn + 64 * s + 16 * kq + col) * DQ + quad * 8);

    unsigned short* pw = &ps[cp * 8192 + (32 * rh + quad * 4) * 128 + ci];
#pragma unroll
    for (int s = 0; s < 2; ++s) {
#pragma unroll
      for (int reg = 0; reg < 4; ++reg) {
        float p0 = __builtin_amdgcn_exp2f(fmaf(c_[s][0][reg], LOG2E, -MOFF));
        float p1 = __builtin_amdgcn_exp2f(fmaf(c_[s][1][reg], LOG2E, -MOFF));
        lp[0][reg] += p0;
        lp[1][reg] += p1;
        const int so = reg * 128 + s * 64 + (kb8 ^ (q4 + reg)) * 8;
        pw[so]        = f2b(p0);
        pw[so + 2048] = f2b(p1);   // row+16: (row&7) unchanged -> same swz
      }
    }
    __syncthreads();   // P(cp) visible; ps-cp readers from 2 chunks ago done

    const short8* pb0 = (const short8*)&ps[cp * 8192 + col * 128 + ob * 8];
    const short8* pb1 = (const short8*)&ps[cp * 8192 + col * 128 + (ob ^ 4) * 8];
    __builtin_amdgcn_s_setprio(1);
#pragma unroll
    for (int s = 0; s < 2; ++s) {
#pragma unroll
      for (int rg = 0; rg < 4; ++rg) {
        short8 pf0 = pb0[rg * 256 + s * 8];   // rows 16rg, keys s*64+quad*8
        short8 pf1 = pb1[rg * 256 + s * 8];   // keys s*64+32+quad*8
#pragma unroll
        for (int ct = 0; ct < 2; ++ct) {
          acc[rg][ct] = __builtin_amdgcn_mfma_f32_16x16x32_bf16(pf0, vf[s][ct][0], acc[rg][ct], 0, 0, 0);
          acc[rg][ct] = __builtin_amdgcn_mfma_f32_16x16x32_bf16(pf1, vf[s][ct][1], acc[rg][ct], 0, 0, 0);
        }
      }
    }
    __builtin_amdgcn_s_setprio(0);
  }

  // ---------------- l reduction ----------------
#pragma unroll
  for (int rgp = 0; rgp < 2; ++rgp)
#pragma unroll
    for (int reg = 0; reg < 4; ++reg) {
#pragma unroll
      for (int mask = 1; mask <= 8; mask <<= 1)
        lp[rgp][reg] += __shfl_xor(lp[rgp][reg], mask);
    }
  if (col == 0) {
#pragma unroll
    for (int rgp = 0; rgp < 2; ++rgp)
#pragma unroll
      for (int reg = 0; reg < 4; ++reg)
        buf[kq][32 * rh + 16 * rgp + quad * 4 + reg] = lp[rgp][reg];
  }
  __syncthreads();
  if (kq == 0 && col == 0) {
#pragma unroll
    for (int rgp = 0; rgp < 2; ++rgp)
#pragma unroll
      for (int reg = 0; reg < 4; ++reg) {
        int row = 32 * rh + 16 * rgp + quad * 4 + reg;
        lf[row] = 1.0f / (buf[0][row] + buf[1][row] + buf[2][row] + buf[3][row]);
      }
  }
  __syncthreads();

  // ---------------- epilogue: normalize + residual + store ----------------
#pragma unroll
  for (int rg = 0; rg < 4; ++rg) {
    float linv[4];
#pragma unroll
    for (int reg = 0; reg < 4; ++reg)
      linv[reg] = lf[16 * rg + quad * 4 + reg];
#pragma unroll
    for (int ct = 0; ct < 2; ++ct) {
      int c  = 32 * w + 16 * ct + col;
      int ib = i0 + 16 * rg + quad * 4;
      size_t idx = ((size_t)bg * CH + c) * NSP + ib;
      float4 xr = *(const float4*)&x[idx];
      float4 o;
      o.x = acc[rg][ct][0] * linv[0] + xr.x;
      o.y = acc[rg][ct][1] * linv[1] + xr.y;
      o.z = acc[rg][ct][2] * linv[2] + xr.z;
      o.w = acc[rg][ct][3] * linv[3] + xr.w;
      *(float4*)&out[idx] = o;
    }
  }
}

// ---------------------------------------------------------------- launch ----
extern "C" void kernel_launch(void* const* d_in, const int* in_sizes, int n_in,
                              void* d_out, int out_size, void* d_ws, size_t ws_size,
                              hipStream_t stream) {
  (void)in_sizes; (void)n_in; (void)out_size;
  const float* x  = (const float*)d_in[0];
  const float* wq = (const float*)d_in[1];
  const float* bq = (const float*)d_in[2];
  const float* wk = (const float*)d_in[3];
  const float* bk = (const float*)d_in[4];
  const float* wv = (const float*)d_in[5];
  const float* bv = (const float*)d_in[6];
  float* out = (float*)d_out;

  const size_t WALL_B = (size_t)RWS * CH * sizeof(float) + 4096;  // wh+wl+ball
  const size_t QB_B = (size_t)NSP * DQ * sizeof(unsigned short);  // 256 KiB
  const size_t VB_B = (size_t)CH * NSP * sizeof(unsigned short);  //   2 MiB
  const size_t PER_B = 2 * QB_B + VB_B;                           // 2.5 MiB/batch

  int ns = 8;
  while (ns > 1 && WALL_B + (size_t)ns * PER_B > ws_size) ns >>= 1;

  char* ws = (char*)d_ws;
  unsigned short* wh = (unsigned short*)ws;
  unsigned short* wl = wh + (size_t)RWS * CH;
  float* ball = (float*)(ws + (size_t)RWS * CH * 2 * sizeof(unsigned short));
  char* qkv = ws + WALL_B;
  unsigned short* qb = (unsigned short*)qkv;
  unsigned short* kb = (unsigned short*)(qkv + (size_t)ns * QB_B);
  unsigned short* vb = (unsigned short*)(qkv + (size_t)ns * 2 * QB_B);

  prep_kernel<<<dim3(RWS), dim3(256), 0, stream>>>(wq, bq, wk, bk, wv, bv, wh, wl, ball);
  for (int b0 = 0; b0 < 8; b0 += ns) {
    proj_kernel<<<dim3(64, 1, ns), dim3(256), 0, stream>>>(
        x, wh, wl, ball, qb, kb, vb, b0);
    attn_kernel<<<dim3(64 * ns), dim3(512), 0, stream>>>(
        x, qb, kb, vb, out, b0, ns);
  }
}